// Round 24
// baseline (630.756 us; speedup 1.0000x reference)
//
#include <hip/hip_runtime.h>
#include <math.h>

#define N_NODES 50000
#define N_EDGESX 800000
#define E_TOT   (N_EDGESX + N_NODES)
#define HEADS 8
#define HID 64
#define HH512 (HID*HEADS)     // 512
#define OUTC 47
#define NEG_SLOPE 0.2f

typedef float f32x4 __attribute__((ext_vector_type(4)));
typedef short s16x8 __attribute__((ext_vector_type(8)));   // 8 bf16 (4 VGPRs)
typedef short s16x4 __attribute__((ext_vector_type(4)));

__device__ __forceinline__ float lrelu(float x) { return x > 0.f ? x : NEG_SLOPE * x; }

// f32 -> bf16 bits, round-to-nearest-even (finite inputs)
__device__ __forceinline__ short f2bf(float f) {
    unsigned u = __float_as_uint(f);
    unsigned r = (u + 0x7FFFu + ((u >> 16) & 1u)) >> 16;
    return (short)r;
}
__device__ __forceinline__ float bf2f(unsigned short b) {
    return __uint_as_float(((unsigned)b) << 16);
}

// async global->LDS, 16B per lane; lds dest = wave-uniform base + lane*16
__device__ __forceinline__ void gload_lds16(const short* gp, short* lp) {
    __builtin_amdgcn_global_load_lds(
        (const __attribute__((address_space(1))) unsigned int*)gp,
        (__attribute__((address_space(3))) unsigned int*)lp, 16, 0, 0);
}

// ---------------- bf16 MFMA GEMM (global_load_lds, BK=64, XOR-swizzled slots) ----------------
// NOTE: all acc-indexing loops MUST have compile-time bounds (rule #20).
#define GBM 128
#define GBN 128
#define GBK 64
__global__ __launch_bounds__(256) void gemm_bf16(const short* __restrict__ A,
                                                 const short* __restrict__ Bt,
                                                 unsigned short* __restrict__ C,
                                                 int M, int N, int K,
                                                 const float* __restrict__ a_s,
                                                 const float* __restrict__ a_d,
                                                 float* __restrict__ alsp,
                                                 float* __restrict__ aldp,
                                                 int logitC, int nheads) {
    __shared__ short As[GBM][GBK];
    __shared__ short Bs[GBN][GBK];
    int tid = threadIdx.x;
    int lane = tid & 63;
    int wave = tid >> 6;
    int wr = wave >> 1, wc = wave & 1;      // 2x2 wave grid, 64x64 per wave
    int brow = blockIdx.x * GBM, bcol = blockIdx.y * GBN;
    int lr = lane & 15;
    int sg = lane >> 4;                      // k-quarter 0..3 within 32-k half
    int r8 = lane >> 3, sl = lane & 7;
    int gslot = sl ^ r8;                     // row%8 == r8 (rowbase multiple of 8)
    int nvalid = N - bcol; if (nvalid > GBN) nvalid = GBN;
    if (nvalid < GBN) {
        for (int c = tid; c < (GBN - nvalid) * (GBK / 8); c += 256) {
            int row = nvalid + c / (GBK / 8), slot = c % (GBK / 8);
            *(s16x8*)&Bs[row][slot * 8] = (s16x8){};
        }
    }
    f32x4 acc[4][4] = {};
    for (int k0 = 0; k0 < K; k0 += GBK) {
        #pragma unroll
        for (int it = 0; it < 4; ++it) {                 // A: wave covers 32 rows
            int rowbase = wave * 32 + it * 8;
            gload_lds16(A + (size_t)(brow + rowbase + r8) * K + k0 + gslot * 8,
                        &As[rowbase][0]);
        }
        #pragma unroll
        for (int it = 0; it < 4; ++it) {                 // B: wave covers 32 rows
            int rowbase = wave * 32 + it * 8;
            if (rowbase + r8 < nvalid)
                gload_lds16(Bt + (size_t)(bcol + rowbase + r8) * K + k0 + gslot * 8,
                            &Bs[rowbase][0]);
        }
        __syncthreads();   // drains vmcnt (incl. global_load_lds)
        #pragma unroll
        for (int kk = 0; kk < 2; ++kk) {
            int rslot = (kk * 4 + sg) ^ (lr & 7);
            s16x8 af[4], bfr[4];
            #pragma unroll
            for (int m = 0; m < 4; ++m) af[m] = *(const s16x8*)&As[wr * 64 + m * 16 + lr][rslot * 8];
            #pragma unroll
            for (int n = 0; n < 4; ++n) bfr[n] = *(const s16x8*)&Bs[wc * 64 + n * 16 + lr][rslot * 8];
            #pragma unroll
            for (int m = 0; m < 4; ++m)
                #pragma unroll
                for (int n = 0; n < 4; ++n)
                    acc[m][n] = __builtin_amdgcn_mfma_f32_16x16x32_bf16(af[m], bfr[n], acc[m][n], 0, 0, 0);
        }
        __syncthreads();
    }
    int r4 = (lane >> 4) * 4;   // C/D: col = lane&15, row = (lane>>4)*4 + i
    #pragma unroll
    for (int m = 0; m < 4; ++m) {
        #pragma unroll
        for (int n = 0; n < 4; ++n) {
            int col = bcol + wc * 64 + n * 16 + lr;
            if (col >= N) continue;
            #pragma unroll
            for (int i = 0; i < 4; ++i) {
                int row = brow + wr * 64 + m * 16 + r4 + i;
                if (row < M) C[(size_t)row * N + col] = (unsigned short)f2bf(acc[m][n][i]);
            }
        }
    }
    // ---- fused logits ----
    if (alsp) {
        int colbase = bcol + wc * 64;
        bool active = (logitC == 64) || (colbase == 0);
        if (active) {
            int h = (logitC == 64) ? (colbase >> 6) : 0;
            float asr[4], adr[4];
            #pragma unroll
            for (int n = 0; n < 4; ++n) {
                int c = n * 16 + lr;
                asr[n] = (c < logitC) ? a_s[h * logitC + c] : 0.f;
                adr[n] = (c < logitC) ? a_d[h * logitC + c] : 0.f;
            }
            #pragma unroll
            for (int m = 0; m < 4; ++m) {
                #pragma unroll
                for (int i = 0; i < 4; ++i) {
                    float vs = 0.f, vd = 0.f;
                    #pragma unroll
                    for (int n = 0; n < 4; ++n) {
                        vs += acc[m][n][i] * asr[n];
                        vd += acc[m][n][i] * adr[n];
                    }
                    #pragma unroll
                    for (int off = 1; off < 16; off <<= 1) {
                        vs += __shfl_xor(vs, off);
                        vd += __shfl_xor(vd, off);
                    }
                    int row = brow + wr * 64 + m * 16 + r4 + i;
                    if (lr == 0 && row < M) {
                        alsp[(size_t)row * nheads + h] = vs;
                        aldp[(size_t)row * nheads + h] = vd;
                    }
                }
            }
        }
    }
}

// ---------------- casts ----------------
__global__ void cast_bf16_k(const float* __restrict__ in, short* __restrict__ outb, long long n) {
    long long i = ((long long)blockIdx.x * blockDim.x + threadIdx.x) * 4;
    if (i >= n) return;
    float4 f = *(const float4*)(in + i);
    s16x4 o = {f2bf(f.x), f2bf(f.y), f2bf(f.z), f2bf(f.w)};
    *(s16x4*)(outb + i) = o;
}

// W[K][N] f32 -> Wt[N][K] bf16
__global__ void wt_cast_k(const float* __restrict__ W, short* __restrict__ Wt, int K, int N) {
    int t = blockIdx.x * blockDim.x + threadIdx.x;
    if (t >= K * N) return;
    int k = t / N, n = t - k * N;
    Wt[(size_t)n * K + k] = f2bf(W[t]);
}

// ---------------- CSR build ----------------
__global__ void deg_count_k(const int* __restrict__ ei, int* __restrict__ deg) {
    int e = blockIdx.x * blockDim.x + threadIdx.x;
    if (e >= E_TOT) return;
    int d = (e < N_EDGESX) ? ei[N_EDGESX + e] : e - N_EDGESX;
    atomicAdd(&deg[d], 1);
}

// shuffle-based scan: 2 barriers per 1024-chunk
__global__ __launch_bounds__(1024) void scan_k(int* __restrict__ pos, int* __restrict__ rowptr) {
    __shared__ int wsum[16];
    __shared__ int carry_s;
    int tid = threadIdx.x, lane = tid & 63, w = tid >> 6;
    if (tid == 0) carry_s = 0;
    __syncthreads();
    for (int base = 0; base < N_NODES; base += 1024) {
        int i = base + tid;
        int v = (i < N_NODES) ? pos[i] : 0;
        int sc = v;
        #pragma unroll
        for (int off = 1; off < 64; off <<= 1) {
            int t = __shfl_up(sc, off);
            if (lane >= off) sc += t;
        }
        if (lane == 63) wsum[w] = sc;
        __syncthreads();
        if (w == 0 && lane < 16) {
            int s = wsum[lane];
            #pragma unroll
            for (int off = 1; off < 16; off <<= 1) {
                int t = __shfl_up(s, off);
                if (lane >= off) s += t;
            }
            wsum[lane] = s;
        }
        __syncthreads();
        int wbase = (w > 0) ? wsum[w - 1] : 0;
        int excl = carry_s + wbase + sc - v;
        if (i < N_NODES) { rowptr[i] = excl; pos[i] = excl; }
        __syncthreads();
        if (tid == 1023) carry_s += wsum[15];
        __syncthreads();
    }
    if (threadIdx.x == 0) rowptr[N_NODES] = carry_s;
}

__global__ void scatter_k(const int* __restrict__ ei, int* __restrict__ pos,
                          int* __restrict__ csr_src) {
    int e = blockIdx.x * blockDim.x + threadIdx.x;
    if (e >= E_TOT) return;
    int s, d;
    if (e < N_EDGESX) { s = ei[e]; d = ei[N_EDGESX + e]; }
    else              { s = e - N_EDGESX; d = s; }
    int idx = atomicAdd(&pos[d], 1);
    csr_src[idx] = s;
}

// ---------------- fused NO-MAX softmax+aggregate, H=8, C=64 ----------------
__global__ __launch_bounds__(256) void node_agg8_k(
    const int* __restrict__ rowptr, const int* __restrict__ csr_src,
    const float* __restrict__ als, const float* __restrict__ ald,
    const unsigned short* __restrict__ hb, const float* __restrict__ bias,
    short* __restrict__ out) {
    int node = (blockIdx.x << 2) + (threadIdx.x >> 6);
    int lane = threadIdx.x & 63;
    if (node >= N_NODES) return;
    int beg = rowptr[node], end = rowptr[node + 1];
    int eh_e = lane >> 3, eh_h = lane & 7;
    float adv = ald[(size_t)node * 8 + eh_h];
    float den = 0.f;
    float acc[8] = {};
    int i = beg + eh_e;
    int s_cur = csr_src[i < end ? i : (end - 1)];
    for (int c0 = beg; c0 < end; c0 += 8, i += 8) {
        bool valid = (i < end);
        int inx = i + 8;
        int s_next = csr_src[inx < end ? inx : (end - 1)];   // prefetch next chunk
        float v = lrelu(als[(size_t)s_cur * 8 + eh_h] + adv);
        float p = valid ? expf(v) : 0.f;
        den += p;
        #pragma unroll
        for (int e = 0; e < 8; ++e) {
            if (c0 + e >= end) break;              // uniform across wave
            int se = __shfl(s_cur, e * 8);
            const unsigned short* hrow = hb + (size_t)se * HH512;
            #pragma unroll
            for (int j = 0; j < 8; ++j) {
                float pj = __shfl(p, e * 8 + j);
                acc[j] += pj * bf2f(hrow[j * 64 + lane]);
            }
        }
        s_cur = s_next;
    }
    den += __shfl_xor(den, 8);
    den += __shfl_xor(den, 16);
    den += __shfl_xor(den, 32);
    size_t ob = (size_t)node * HH512;
    #pragma unroll
    for (int j = 0; j < 8; ++j) {
        float dj = __shfl(den, j);
        float r = acc[j] / (dj + 1e-16f) + bias[j * 64 + lane];
        out[ob + j * 64 + lane] = f2bf(fmaxf(r, 0.f));
    }
}

// ---------------- final layer: H=1, C=47, NO-MAX softmax, group-of-8 unconditional gathers ----------------
// Inner loop has NO break between loads: 8 clamped gathers issue back-to-back (8x MLP),
// invalid edges contribute pe=0. Waste <= 7 x 94B per node (L3-resident).
__global__ __launch_bounds__(256) void node_agg_final_k(
    const int* __restrict__ rowptr, const int* __restrict__ csr_src,
    const float* __restrict__ als, const float* __restrict__ ald,
    const unsigned short* __restrict__ hb, const float* __restrict__ b3,
    float* __restrict__ out) {
    int node = (blockIdx.x << 2) + (threadIdx.x >> 6);
    int lane = threadIdx.x & 63;
    if (node >= N_NODES) return;
    int beg = rowptr[node], end = rowptr[node + 1];
    float ad = ald[node];
    float den = 0.f, acc = 0.f;
    int i = beg + lane;
    int s_cur = csr_src[i < end ? i : (end - 1)];
    for (int c0 = beg; c0 < end; c0 += 64, i += 64) {
        bool valid = (i < end);
        int inx = i + 64;
        int s_next = csr_src[inx < end ? inx : (end - 1)];   // prefetch
        float v = lrelu(als[s_cur] + ad);
        float p = valid ? expf(v) : 0.f;
        den += p;
        int ne = end - c0; if (ne > 64) ne = 64;             // wave-uniform
        for (int g = 0; g < ne; g += 8) {                    // group loop, no inner break
            #pragma unroll
            for (int u = 0; u < 8; ++u) {
                int e = g + u;                               // e <= 63 always (g<=56)
                int se = __shfl(s_cur, e);                   // clamped edge for e>=ne
                float pe = (e < ne) ? __shfl(p, e) : 0.f;
                float hv = (lane < OUTC) ? bf2f(hb[(size_t)se * OUTC + lane]) : 0.f;
                acc += pe * hv;
            }
        }
        s_cur = s_next;
    }
    #pragma unroll
    for (int off = 32; off; off >>= 1) den += __shfl_xor(den, off);
    float r = (lane < OUTC) ? acc / (den + 1e-16f) + b3[lane] : -INFINITY;
    float mx = r;
    #pragma unroll
    for (int off = 32; off; off >>= 1) mx = fmaxf(mx, __shfl_xor(mx, off));
    float ex = (lane < OUTC) ? expf(r - mx) : 0.f;
    float sum = ex;
    #pragma unroll
    for (int off = 32; off; off >>= 1) sum += __shfl_xor(sum, off);
    if (lane < OUTC) out[(size_t)node * OUTC + lane] = r - mx - logf(sum);
}

static inline int cdiv(long long a, long long b) { return (int)((a + b - 1) / b); }

extern "C" void kernel_launch(void* const* d_in, const int* in_sizes, int n_in,
                              void* d_out, int out_size, void* d_ws, size_t ws_size,
                              hipStream_t stream) {
    const float* x   = (const float*)d_in[0];
    const int*   ei  = (const int*)d_in[1];
    const float* W1  = (const float*)d_in[2];
    const float* as1 = (const float*)d_in[3];
    const float* ad1 = (const float*)d_in[4];
    const float* b1  = (const float*)d_in[5];
    const float* W2  = (const float*)d_in[6];
    const float* as2 = (const float*)d_in[7];
    const float* ad2 = (const float*)d_in[8];
    const float* b2  = (const float*)d_in[9];
    const float* W3  = (const float*)d_in[10];
    const float* as3 = (const float*)d_in[11];
    const float* ad3 = (const float*)d_in[12];
    const float* b3  = (const float*)d_in[13];
    float* out = (float*)d_out;

    short* Abf = (short*)d_ws;                                     // [N,512] bf16
    unsigned short* Hb = (unsigned short*)(Abf + (size_t)N_NODES * HH512); // [N,512] bf16
    float* als = (float*)(Hb + (size_t)N_NODES * HH512);           // [N,8]
    float* ald = als + (size_t)N_NODES * HEADS;                    // [N,8]
    short* Wt  = (short*)(ald + (size_t)N_NODES * HEADS);          // [512,512] bf16
    int* rowptr  = (int*)(Wt + (size_t)HH512 * HH512);             // [N+1]
    int* pos     = rowptr + (N_NODES + 1);                         // [N]
    int* csr_src = pos + N_NODES;                                  // [E_TOT]

    dim3 blk(256);

    // ---- CSR build (reused by all 3 layers) ----
    hipMemsetAsync(pos, 0, (size_t)N_NODES * 4, stream);
    deg_count_k<<<cdiv(E_TOT, 256), blk, 0, stream>>>(ei, pos);
    scan_k<<<1, 1024, 0, stream>>>(pos, rowptr);
    scatter_k<<<cdiv(E_TOT, 256), blk, 0, stream>>>(ei, pos, csr_src);

    // ================= Layer 1 =================
    cast_bf16_k<<<cdiv((long long)N_NODES * 256 / 4, 256), blk, 0, stream>>>(x, Abf, (long long)N_NODES * 256);
    wt_cast_k<<<cdiv(256 * HH512, 256), blk, 0, stream>>>(W1, Wt, 256, HH512);
    gemm_bf16<<<dim3(cdiv(N_NODES, GBM), HH512 / GBN), blk, 0, stream>>>(
        Abf, Wt, Hb, N_NODES, HH512, 256, as1, ad1, als, ald, 64, HEADS);
    node_agg8_k<<<cdiv(N_NODES, 4), blk, 0, stream>>>(rowptr, csr_src, als, ald, Hb, b1, Abf);

    // ================= Layer 2 =================
    wt_cast_k<<<cdiv(HH512 * HH512, 256), blk, 0, stream>>>(W2, Wt, HH512, HH512);
    gemm_bf16<<<dim3(cdiv(N_NODES, GBM), HH512 / GBN), blk, 0, stream>>>(
        Abf, Wt, Hb, N_NODES, HH512, HH512, as2, ad2, als, ald, 64, HEADS);
    node_agg8_k<<<cdiv(N_NODES, 4), blk, 0, stream>>>(rowptr, csr_src, als, ald, Hb, b2, Abf);

    // ================= Layer 3 =================
    wt_cast_k<<<cdiv(HH512 * OUTC, 256), blk, 0, stream>>>(W3, Wt, HH512, OUTC);
    gemm_bf16<<<dim3(cdiv(N_NODES, GBM), 1), blk, 0, stream>>>(
        Abf, Wt, Hb, N_NODES, OUTC, HH512, as3, ad3, als, ald, 47, 1);
    node_agg_final_k<<<cdiv(N_NODES, 4), blk, 0, stream>>>(rowptr, csr_src, als, ald, Hb, b3, out);
}

// Round 25
// 585.411 us; speedup vs baseline: 1.0775x; 1.0775x over previous
//
#include <hip/hip_runtime.h>
#include <math.h>

#define N_NODES 50000
#define N_EDGESX 800000
#define E_TOT   (N_EDGESX + N_NODES)
#define HEADS 8
#define HID 64
#define HH512 (HID*HEADS)     // 512
#define OUTC 47
#define NEG_SLOPE 0.2f

typedef float f32x4 __attribute__((ext_vector_type(4)));
typedef short s16x8 __attribute__((ext_vector_type(8)));   // 8 bf16 (4 VGPRs)
typedef short s16x4 __attribute__((ext_vector_type(4)));

__device__ __forceinline__ float lrelu(float x) { return x > 0.f ? x : NEG_SLOPE * x; }

// f32 -> bf16 bits, round-to-nearest-even (finite inputs)
__device__ __forceinline__ short f2bf(float f) {
    unsigned u = __float_as_uint(f);
    unsigned r = (u + 0x7FFFu + ((u >> 16) & 1u)) >> 16;
    return (short)r;
}
__device__ __forceinline__ float bf2f(unsigned short b) {
    return __uint_as_float(((unsigned)b) << 16);
}

// async global->LDS, 16B per lane; lds dest = wave-uniform base + lane*16
__device__ __forceinline__ void gload_lds16(const short* gp, short* lp) {
    __builtin_amdgcn_global_load_lds(
        (const __attribute__((address_space(1))) unsigned int*)gp,
        (__attribute__((address_space(3))) unsigned int*)lp, 16, 0, 0);
}

// ---------------- bf16 MFMA GEMM (global_load_lds, BK=64, XOR-swizzled slots) ----------------
// NOTE: all acc-indexing loops MUST have compile-time bounds (rule #20).
#define GBM 128
#define GBN 128
#define GBK 64
__global__ __launch_bounds__(256) void gemm_bf16(const short* __restrict__ A,
                                                 const short* __restrict__ Bt,
                                                 unsigned short* __restrict__ C,
                                                 int M, int N, int K,
                                                 const float* __restrict__ a_s,
                                                 const float* __restrict__ a_d,
                                                 float* __restrict__ alsp,
                                                 float* __restrict__ aldp,
                                                 int logitC, int nheads) {
    __shared__ short As[GBM][GBK];
    __shared__ short Bs[GBN][GBK];
    int tid = threadIdx.x;
    int lane = tid & 63;
    int wave = tid >> 6;
    int wr = wave >> 1, wc = wave & 1;      // 2x2 wave grid, 64x64 per wave
    int brow = blockIdx.x * GBM, bcol = blockIdx.y * GBN;
    int lr = lane & 15;
    int sg = lane >> 4;                      // k-quarter 0..3 within 32-k half
    int r8 = lane >> 3, sl = lane & 7;
    int gslot = sl ^ r8;                     // row%8 == r8 (rowbase multiple of 8)
    int nvalid = N - bcol; if (nvalid > GBN) nvalid = GBN;
    if (nvalid < GBN) {
        for (int c = tid; c < (GBN - nvalid) * (GBK / 8); c += 256) {
            int row = nvalid + c / (GBK / 8), slot = c % (GBK / 8);
            *(s16x8*)&Bs[row][slot * 8] = (s16x8){};
        }
    }
    f32x4 acc[4][4] = {};
    for (int k0 = 0; k0 < K; k0 += GBK) {
        #pragma unroll
        for (int it = 0; it < 4; ++it) {                 // A: wave covers 32 rows
            int rowbase = wave * 32 + it * 8;
            gload_lds16(A + (size_t)(brow + rowbase + r8) * K + k0 + gslot * 8,
                        &As[rowbase][0]);
        }
        #pragma unroll
        for (int it = 0; it < 4; ++it) {                 // B: wave covers 32 rows
            int rowbase = wave * 32 + it * 8;
            if (rowbase + r8 < nvalid)
                gload_lds16(Bt + (size_t)(bcol + rowbase + r8) * K + k0 + gslot * 8,
                            &Bs[rowbase][0]);
        }
        __syncthreads();   // drains vmcnt (incl. global_load_lds)
        #pragma unroll
        for (int kk = 0; kk < 2; ++kk) {
            int rslot = (kk * 4 + sg) ^ (lr & 7);
            s16x8 af[4], bfr[4];
            #pragma unroll
            for (int m = 0; m < 4; ++m) af[m] = *(const s16x8*)&As[wr * 64 + m * 16 + lr][rslot * 8];
            #pragma unroll
            for (int n = 0; n < 4; ++n) bfr[n] = *(const s16x8*)&Bs[wc * 64 + n * 16 + lr][rslot * 8];
            #pragma unroll
            for (int m = 0; m < 4; ++m)
                #pragma unroll
                for (int n = 0; n < 4; ++n)
                    acc[m][n] = __builtin_amdgcn_mfma_f32_16x16x32_bf16(af[m], bfr[n], acc[m][n], 0, 0, 0);
        }
        __syncthreads();
    }
    int r4 = (lane >> 4) * 4;   // C/D: col = lane&15, row = (lane>>4)*4 + i
    #pragma unroll
    for (int m = 0; m < 4; ++m) {
        #pragma unroll
        for (int n = 0; n < 4; ++n) {
            int col = bcol + wc * 64 + n * 16 + lr;
            if (col >= N) continue;
            #pragma unroll
            for (int i = 0; i < 4; ++i) {
                int row = brow + wr * 64 + m * 16 + r4 + i;
                if (row < M) C[(size_t)row * N + col] = (unsigned short)f2bf(acc[m][n][i]);
            }
        }
    }
    // ---- fused logits ----
    if (alsp) {
        int colbase = bcol + wc * 64;
        bool active = (logitC == 64) || (colbase == 0);
        if (active) {
            int h = (logitC == 64) ? (colbase >> 6) : 0;
            float asr[4], adr[4];
            #pragma unroll
            for (int n = 0; n < 4; ++n) {
                int c = n * 16 + lr;
                asr[n] = (c < logitC) ? a_s[h * logitC + c] : 0.f;
                adr[n] = (c < logitC) ? a_d[h * logitC + c] : 0.f;
            }
            #pragma unroll
            for (int m = 0; m < 4; ++m) {
                #pragma unroll
                for (int i = 0; i < 4; ++i) {
                    float vs = 0.f, vd = 0.f;
                    #pragma unroll
                    for (int n = 0; n < 4; ++n) {
                        vs += acc[m][n][i] * asr[n];
                        vd += acc[m][n][i] * adr[n];
                    }
                    #pragma unroll
                    for (int off = 1; off < 16; off <<= 1) {
                        vs += __shfl_xor(vs, off);
                        vd += __shfl_xor(vd, off);
                    }
                    int row = brow + wr * 64 + m * 16 + r4 + i;
                    if (lr == 0 && row < M) {
                        alsp[(size_t)row * nheads + h] = vs;
                        aldp[(size_t)row * nheads + h] = vd;
                    }
                }
            }
        }
    }
}

// ---------------- casts ----------------
__global__ void cast_bf16_k(const float* __restrict__ in, short* __restrict__ outb, long long n) {
    long long i = ((long long)blockIdx.x * blockDim.x + threadIdx.x) * 4;
    if (i >= n) return;
    float4 f = *(const float4*)(in + i);
    s16x4 o = {f2bf(f.x), f2bf(f.y), f2bf(f.z), f2bf(f.w)};
    *(s16x4*)(outb + i) = o;
}

// W[K][N] f32 -> Wt[N][K] bf16
__global__ void wt_cast_k(const float* __restrict__ W, short* __restrict__ Wt, int K, int N) {
    int t = blockIdx.x * blockDim.x + threadIdx.x;
    if (t >= K * N) return;
    int k = t / N, n = t - k * N;
    Wt[(size_t)n * K + k] = f2bf(W[t]);
}

// ---------------- CSR build ----------------
__global__ void deg_count_k(const int* __restrict__ ei, int* __restrict__ deg) {
    int e = blockIdx.x * blockDim.x + threadIdx.x;
    if (e >= E_TOT) return;
    int d = (e < N_EDGESX) ? ei[N_EDGESX + e] : e - N_EDGESX;
    atomicAdd(&deg[d], 1);
}

// parallel scan, phase 1: per-block (1024) exclusive scan + block sum
__global__ __launch_bounds__(1024) void scan1_k(const int* __restrict__ deg,
                                                int* __restrict__ partial,
                                                int* __restrict__ blocksum) {
    __shared__ int wsum[16];
    int tid = threadIdx.x, lane = tid & 63, w = tid >> 6;
    int i = blockIdx.x * 1024 + tid;
    int v = (i < N_NODES) ? deg[i] : 0;
    int sc = v;
    #pragma unroll
    for (int off = 1; off < 64; off <<= 1) {
        int t = __shfl_up(sc, off);
        if (lane >= off) sc += t;
    }
    if (lane == 63) wsum[w] = sc;
    __syncthreads();
    if (w == 0 && lane < 16) {
        int s = wsum[lane];
        #pragma unroll
        for (int off = 1; off < 16; off <<= 1) {
            int t = __shfl_up(s, off);
            if (lane >= off) s += t;
        }
        wsum[lane] = s;
    }
    __syncthreads();
    int wbase = (w > 0) ? wsum[w - 1] : 0;
    int excl = wbase + sc - v;
    if (i < N_NODES) partial[i] = excl;
    if (tid == 1023) blocksum[blockIdx.x] = excl + v;   // block total
}

// phase 2: single wave scans block sums (nb <= 64) -> exclusive
__global__ void scan2_k(int* __restrict__ blocksum, int nb) {
    int lane = threadIdx.x & 63;
    int v = (lane < nb) ? blocksum[lane] : 0;
    int sc = v;
    #pragma unroll
    for (int off = 1; off < 64; off <<= 1) {
        int t = __shfl_up(sc, off);
        if (lane >= off) sc += t;
    }
    if (lane < nb) blocksum[lane] = sc - v;             // exclusive
}

// phase 3: add block offsets -> rowptr & pos
__global__ void scan3_k(const int* __restrict__ partial, const int* __restrict__ blocksum,
                        int* __restrict__ rowptr, int* __restrict__ pos) {
    int i = blockIdx.x * blockDim.x + threadIdx.x;
    if (i == 0) rowptr[N_NODES] = E_TOT;                // total is a constant
    if (i >= N_NODES) return;
    int e = partial[i] + blocksum[i >> 10];
    rowptr[i] = e;
    pos[i] = e;
}

__global__ void scatter_k(const int* __restrict__ ei, int* __restrict__ pos,
                          int* __restrict__ csr_src) {
    int e = blockIdx.x * blockDim.x + threadIdx.x;
    if (e >= E_TOT) return;
    int s, d;
    if (e < N_EDGESX) { s = ei[e]; d = ei[N_EDGESX + e]; }
    else              { s = e - N_EDGESX; d = s; }
    int idx = atomicAdd(&pos[d], 1);
    csr_src[idx] = s;
}

// ---------------- fused NO-MAX softmax+aggregate, H=8, C=64 ----------------
__global__ __launch_bounds__(256) void node_agg8_k(
    const int* __restrict__ rowptr, const int* __restrict__ csr_src,
    const float* __restrict__ als, const float* __restrict__ ald,
    const unsigned short* __restrict__ hb, const float* __restrict__ bias,
    short* __restrict__ out) {
    int node = (blockIdx.x << 2) + (threadIdx.x >> 6);
    int lane = threadIdx.x & 63;
    if (node >= N_NODES) return;
    int beg = rowptr[node], end = rowptr[node + 1];
    int eh_e = lane >> 3, eh_h = lane & 7;
    float adv = ald[(size_t)node * 8 + eh_h];
    float den = 0.f;
    float acc[8] = {};
    int i = beg + eh_e;
    int s_cur = csr_src[i < end ? i : (end - 1)];
    for (int c0 = beg; c0 < end; c0 += 8, i += 8) {
        bool valid = (i < end);
        int inx = i + 8;
        int s_next = csr_src[inx < end ? inx : (end - 1)];   // prefetch next chunk
        float v = lrelu(als[(size_t)s_cur * 8 + eh_h] + adv);
        float p = valid ? expf(v) : 0.f;
        den += p;
        #pragma unroll
        for (int e = 0; e < 8; ++e) {
            if (c0 + e >= end) break;              // uniform across wave
            int se = __shfl(s_cur, e * 8);
            const unsigned short* hrow = hb + (size_t)se * HH512;
            #pragma unroll
            for (int j = 0; j < 8; ++j) {
                float pj = __shfl(p, e * 8 + j);
                acc[j] += pj * bf2f(hrow[j * 64 + lane]);
            }
        }
        s_cur = s_next;
    }
    den += __shfl_xor(den, 8);
    den += __shfl_xor(den, 16);
    den += __shfl_xor(den, 32);
    size_t ob = (size_t)node * HH512;
    #pragma unroll
    for (int j = 0; j < 8; ++j) {
        float dj = __shfl(den, j);
        float r = acc[j] / (dj + 1e-16f) + bias[j * 64 + lane];
        out[ob + j * 64 + lane] = f2bf(fmaxf(r, 0.f));
    }
}

// ---------------- final layer: H=1, C=47, NO-MAX softmax + bias + log_softmax (r22 best) ----------------
__global__ __launch_bounds__(256) void node_agg_final_k(
    const int* __restrict__ rowptr, const int* __restrict__ csr_src,
    const float* __restrict__ als, const float* __restrict__ ald,
    const unsigned short* __restrict__ hb, const float* __restrict__ b3,
    float* __restrict__ out) {
    int node = (blockIdx.x << 2) + (threadIdx.x >> 6);
    int lane = threadIdx.x & 63;
    if (node >= N_NODES) return;
    int beg = rowptr[node], end = rowptr[node + 1];
    float ad = ald[node];
    float den = 0.f, acc = 0.f;
    int i = beg + lane;
    int s_cur = csr_src[i < end ? i : (end - 1)];
    for (int c0 = beg; c0 < end; c0 += 64, i += 64) {
        bool valid = (i < end);
        int inx = i + 64;
        int s_next = csr_src[inx < end ? inx : (end - 1)];   // prefetch
        float v = lrelu(als[s_cur] + ad);
        float p = valid ? expf(v) : 0.f;
        den += p;
        #pragma unroll 4
        for (int e = 0; e < 64; ++e) {
            if (c0 + e >= end) break;               // uniform across wave
            int se = __shfl(s_cur, e);
            float pe = __shfl(p, e);
            if (lane < OUTC) acc += pe * bf2f(hb[(size_t)se * OUTC + lane]);
        }
        s_cur = s_next;
    }
    #pragma unroll
    for (int off = 32; off; off >>= 1) den += __shfl_xor(den, off);
    float r = (lane < OUTC) ? acc / (den + 1e-16f) + b3[lane] : -INFINITY;
    float mx = r;
    #pragma unroll
    for (int off = 32; off; off >>= 1) mx = fmaxf(mx, __shfl_xor(mx, off));
    float ex = (lane < OUTC) ? expf(r - mx) : 0.f;
    float sum = ex;
    #pragma unroll
    for (int off = 32; off; off >>= 1) sum += __shfl_xor(sum, off);
    if (lane < OUTC) out[(size_t)node * OUTC + lane] = r - mx - logf(sum);
}

static inline int cdiv(long long a, long long b) { return (int)((a + b - 1) / b); }

extern "C" void kernel_launch(void* const* d_in, const int* in_sizes, int n_in,
                              void* d_out, int out_size, void* d_ws, size_t ws_size,
                              hipStream_t stream) {
    const float* x   = (const float*)d_in[0];
    const int*   ei  = (const int*)d_in[1];
    const float* W1  = (const float*)d_in[2];
    const float* as1 = (const float*)d_in[3];
    const float* ad1 = (const float*)d_in[4];
    const float* b1  = (const float*)d_in[5];
    const float* W2  = (const float*)d_in[6];
    const float* as2 = (const float*)d_in[7];
    const float* ad2 = (const float*)d_in[8];
    const float* b2  = (const float*)d_in[9];
    const float* W3  = (const float*)d_in[10];
    const float* as3 = (const float*)d_in[11];
    const float* ad3 = (const float*)d_in[12];
    const float* b3  = (const float*)d_in[13];
    float* out = (float*)d_out;

    short* Abf = (short*)d_ws;                                     // [N,512] bf16
    unsigned short* Hb = (unsigned short*)(Abf + (size_t)N_NODES * HH512); // [N,512] bf16
    float* als = (float*)(Hb + (size_t)N_NODES * HH512);           // [N,8]
    float* ald = als + (size_t)N_NODES * HEADS;                    // [N,8]
    short* Wt  = (short*)(ald + (size_t)N_NODES * HEADS);          // [512,512] bf16
    int* rowptr  = (int*)(Wt + (size_t)HH512 * HH512);             // [N+1]
    int* pos     = rowptr + (N_NODES + 1);                         // [N]
    int* csr_src = pos + N_NODES;                                  // [E_TOT]
    int* blocksum = csr_src + E_TOT;                               // [64]

    dim3 blk(256);
    int nb = cdiv(N_NODES, 1024);   // 49 <= 64

    // ---- CSR build (parallel scan; reused by all 3 layers) ----
    hipMemsetAsync(pos, 0, (size_t)N_NODES * 4, stream);
    deg_count_k<<<cdiv(E_TOT, 256), blk, 0, stream>>>(ei, pos);
    scan1_k<<<nb, 1024, 0, stream>>>(pos, rowptr, blocksum);       // pos=deg -> rowptr=partial
    scan2_k<<<1, 64, 0, stream>>>(blocksum, nb);
    scan3_k<<<cdiv(N_NODES, 256), blk, 0, stream>>>(rowptr, blocksum, rowptr, pos);
    scatter_k<<<cdiv(E_TOT, 256), blk, 0, stream>>>(ei, pos, csr_src);

    // ================= Layer 1 =================
    cast_bf16_k<<<cdiv((long long)N_NODES * 256 / 4, 256), blk, 0, stream>>>(x, Abf, (long long)N_NODES * 256);
    wt_cast_k<<<cdiv(256 * HH512, 256), blk, 0, stream>>>(W1, Wt, 256, HH512);
    gemm_bf16<<<dim3(cdiv(N_NODES, GBM), HH512 / GBN), blk, 0, stream>>>(
        Abf, Wt, Hb, N_NODES, HH512, 256, as1, ad1, als, ald, 64, HEADS);
    node_agg8_k<<<cdiv(N_NODES, 4), blk, 0, stream>>>(rowptr, csr_src, als, ald, Hb, b1, Abf);

    // ================= Layer 2 =================
    wt_cast_k<<<cdiv(HH512 * HH512, 256), blk, 0, stream>>>(W2, Wt, HH512, HH512);
    gemm_bf16<<<dim3(cdiv(N_NODES, GBM), HH512 / GBN), blk, 0, stream>>>(
        Abf, Wt, Hb, N_NODES, HH512, HH512, as2, ad2, als, ald, 64, HEADS);
    node_agg8_k<<<cdiv(N_NODES, 4), blk, 0, stream>>>(rowptr, csr_src, als, ald, Hb, b2, Abf);

    // ================= Layer 3 =================
    wt_cast_k<<<cdiv(HH512 * OUTC, 256), blk, 0, stream>>>(W3, Wt, HH512, OUTC);
    gemm_bf16<<<dim3(cdiv(N_NODES, GBM), 1), blk, 0, stream>>>(
        Abf, Wt, Hb, N_NODES, OUTC, HH512, as3, ad3, als, ald, 47, 1);
    node_agg_final_k<<<cdiv(N_NODES, 4), blk, 0, stream>>>(rowptr, csr_src, als, ald, Hb, b3, out);
}

// Round 26
// 579.337 us; speedup vs baseline: 1.0888x; 1.0105x over previous
//
#include <hip/hip_runtime.h>
#include <math.h>

#define N_NODES 50000
#define N_EDGESX 800000
#define E_TOT   (N_EDGESX + N_NODES)
#define HEADS 8
#define HID 64
#define HH512 (HID*HEADS)     // 512
#define OUTC 47
#define NEG_SLOPE 0.2f

typedef float f32x4 __attribute__((ext_vector_type(4)));
typedef short s16x8 __attribute__((ext_vector_type(8)));   // 8 bf16 (4 VGPRs)
typedef short s16x4 __attribute__((ext_vector_type(4)));

__device__ __forceinline__ float lrelu(float x) { return x > 0.f ? x : NEG_SLOPE * x; }

// f32 -> bf16 bits, round-to-nearest-even (finite inputs)
__device__ __forceinline__ short f2bf(float f) {
    unsigned u = __float_as_uint(f);
    unsigned r = (u + 0x7FFFu + ((u >> 16) & 1u)) >> 16;
    return (short)r;
}
__device__ __forceinline__ float bf2f(unsigned short b) {
    return __uint_as_float(((unsigned)b) << 16);
}

// async global->LDS, 16B per lane; lds dest = wave-uniform base + lane*16
__device__ __forceinline__ void gload_lds16(const short* gp, short* lp) {
    __builtin_amdgcn_global_load_lds(
        (const __attribute__((address_space(1))) unsigned int*)gp,
        (__attribute__((address_space(3))) unsigned int*)lp, 16, 0, 0);
}

// ---------------- bf16 MFMA GEMM (global_load_lds, BK=64, XOR-swizzled slots) ----------------
// NOTE: all acc-indexing loops MUST have compile-time bounds (rule #20).
#define GBM 128
#define GBN 128
#define GBK 64
__global__ __launch_bounds__(256) void gemm_bf16(const short* __restrict__ A,
                                                 const short* __restrict__ Bt,
                                                 unsigned short* __restrict__ C,
                                                 int M, int N, int K,
                                                 const float* __restrict__ a_s,
                                                 const float* __restrict__ a_d,
                                                 float* __restrict__ alsp,
                                                 float* __restrict__ aldp,
                                                 int logitC, int nheads) {
    __shared__ short As[GBM][GBK];
    __shared__ short Bs[GBN][GBK];
    int tid = threadIdx.x;
    int lane = tid & 63;
    int wave = tid >> 6;
    int wr = wave >> 1, wc = wave & 1;      // 2x2 wave grid, 64x64 per wave
    int brow = blockIdx.x * GBM, bcol = blockIdx.y * GBN;
    int lr = lane & 15;
    int sg = lane >> 4;                      // k-quarter 0..3 within 32-k half
    int r8 = lane >> 3, sl = lane & 7;
    int gslot = sl ^ r8;                     // row%8 == r8 (rowbase multiple of 8)
    int nvalid = N - bcol; if (nvalid > GBN) nvalid = GBN;
    if (nvalid < GBN) {
        for (int c = tid; c < (GBN - nvalid) * (GBK / 8); c += 256) {
            int row = nvalid + c / (GBK / 8), slot = c % (GBK / 8);
            *(s16x8*)&Bs[row][slot * 8] = (s16x8){};
        }
    }
    f32x4 acc[4][4] = {};
    for (int k0 = 0; k0 < K; k0 += GBK) {
        #pragma unroll
        for (int it = 0; it < 4; ++it) {                 // A: wave covers 32 rows
            int rowbase = wave * 32 + it * 8;
            gload_lds16(A + (size_t)(brow + rowbase + r8) * K + k0 + gslot * 8,
                        &As[rowbase][0]);
        }
        #pragma unroll
        for (int it = 0; it < 4; ++it) {                 // B: wave covers 32 rows
            int rowbase = wave * 32 + it * 8;
            if (rowbase + r8 < nvalid)
                gload_lds16(Bt + (size_t)(bcol + rowbase + r8) * K + k0 + gslot * 8,
                            &Bs[rowbase][0]);
        }
        __syncthreads();   // drains vmcnt (incl. global_load_lds)
        #pragma unroll
        for (int kk = 0; kk < 2; ++kk) {
            int rslot = (kk * 4 + sg) ^ (lr & 7);
            s16x8 af[4], bfr[4];
            #pragma unroll
            for (int m = 0; m < 4; ++m) af[m] = *(const s16x8*)&As[wr * 64 + m * 16 + lr][rslot * 8];
            #pragma unroll
            for (int n = 0; n < 4; ++n) bfr[n] = *(const s16x8*)&Bs[wc * 64 + n * 16 + lr][rslot * 8];
            #pragma unroll
            for (int m = 0; m < 4; ++m)
                #pragma unroll
                for (int n = 0; n < 4; ++n)
                    acc[m][n] = __builtin_amdgcn_mfma_f32_16x16x32_bf16(af[m], bfr[n], acc[m][n], 0, 0, 0);
        }
        __syncthreads();
    }
    int r4 = (lane >> 4) * 4;   // C/D: col = lane&15, row = (lane>>4)*4 + i
    #pragma unroll
    for (int m = 0; m < 4; ++m) {
        #pragma unroll
        for (int n = 0; n < 4; ++n) {
            int col = bcol + wc * 64 + n * 16 + lr;
            if (col >= N) continue;
            #pragma unroll
            for (int i = 0; i < 4; ++i) {
                int row = brow + wr * 64 + m * 16 + r4 + i;
                if (row < M) C[(size_t)row * N + col] = (unsigned short)f2bf(acc[m][n][i]);
            }
        }
    }
    // ---- fused logits ----
    if (alsp) {
        int colbase = bcol + wc * 64;
        bool active = (logitC == 64) || (colbase == 0);
        if (active) {
            int h = (logitC == 64) ? (colbase >> 6) : 0;
            float asr[4], adr[4];
            #pragma unroll
            for (int n = 0; n < 4; ++n) {
                int c = n * 16 + lr;
                asr[n] = (c < logitC) ? a_s[h * logitC + c] : 0.f;
                adr[n] = (c < logitC) ? a_d[h * logitC + c] : 0.f;
            }
            #pragma unroll
            for (int m = 0; m < 4; ++m) {
                #pragma unroll
                for (int i = 0; i < 4; ++i) {
                    float vs = 0.f, vd = 0.f;
                    #pragma unroll
                    for (int n = 0; n < 4; ++n) {
                        vs += acc[m][n][i] * asr[n];
                        vd += acc[m][n][i] * adr[n];
                    }
                    #pragma unroll
                    for (int off = 1; off < 16; off <<= 1) {
                        vs += __shfl_xor(vs, off);
                        vd += __shfl_xor(vd, off);
                    }
                    int row = brow + wr * 64 + m * 16 + r4 + i;
                    if (lr == 0 && row < M) {
                        alsp[(size_t)row * nheads + h] = vs;
                        aldp[(size_t)row * nheads + h] = vd;
                    }
                }
            }
        }
    }
}

// ---------------- casts ----------------
__global__ void cast_bf16_k(const float* __restrict__ in, short* __restrict__ outb, long long n) {
    long long i = ((long long)blockIdx.x * blockDim.x + threadIdx.x) * 4;
    if (i >= n) return;
    float4 f = *(const float4*)(in + i);
    s16x4 o = {f2bf(f.x), f2bf(f.y), f2bf(f.z), f2bf(f.w)};
    *(s16x4*)(outb + i) = o;
}

// all three W[K][N] f32 -> Wt[N][K] bf16 transposes in ONE launch
#define W1N (256 * 512)
#define W2N (512 * 512)
#define W3N (512 * 47)
__global__ void wt_cast_all_k(const float* __restrict__ W1, const float* __restrict__ W2,
                              const float* __restrict__ W3, short* __restrict__ Wt1,
                              short* __restrict__ Wt2, short* __restrict__ Wt3) {
    int t = blockIdx.x * blockDim.x + threadIdx.x;
    if (t < W1N) {
        int k = t / 512, n = t - k * 512;
        Wt1[(size_t)n * 256 + k] = f2bf(W1[t]);
    } else if (t < W1N + W2N) {
        int u = t - W1N;
        int k = u / 512, n = u - k * 512;
        Wt2[(size_t)n * 512 + k] = f2bf(W2[u]);
    } else if (t < W1N + W2N + W3N) {
        int u = t - W1N - W2N;
        int k = u / 47, n = u - k * 47;
        Wt3[(size_t)n * 512 + k] = f2bf(W3[u]);
    }
}

// ---------------- CSR build ----------------
__global__ void deg_count_k(const int* __restrict__ ei, int* __restrict__ deg) {
    int e = blockIdx.x * blockDim.x + threadIdx.x;
    if (e >= E_TOT) return;
    int d = (e < N_EDGESX) ? ei[N_EDGESX + e] : e - N_EDGESX;
    atomicAdd(&deg[d], 1);
}

// parallel scan, phase 1: per-block (1024) exclusive scan + block sum
__global__ __launch_bounds__(1024) void scan1_k(const int* __restrict__ deg,
                                                int* __restrict__ partial,
                                                int* __restrict__ blocksum) {
    __shared__ int wsum[16];
    int tid = threadIdx.x, lane = tid & 63, w = tid >> 6;
    int i = blockIdx.x * 1024 + tid;
    int v = (i < N_NODES) ? deg[i] : 0;
    int sc = v;
    #pragma unroll
    for (int off = 1; off < 64; off <<= 1) {
        int t = __shfl_up(sc, off);
        if (lane >= off) sc += t;
    }
    if (lane == 63) wsum[w] = sc;
    __syncthreads();
    if (w == 0 && lane < 16) {
        int s = wsum[lane];
        #pragma unroll
        for (int off = 1; off < 16; off <<= 1) {
            int t = __shfl_up(s, off);
            if (lane >= off) s += t;
        }
        wsum[lane] = s;
    }
    __syncthreads();
    int wbase = (w > 0) ? wsum[w - 1] : 0;
    int excl = wbase + sc - v;
    if (i < N_NODES) partial[i] = excl;
    if (tid == 1023) blocksum[blockIdx.x] = excl + v;   // block total
}

// phase 2: single wave scans block sums (nb <= 64) -> exclusive
__global__ void scan2_k(int* __restrict__ blocksum, int nb) {
    int lane = threadIdx.x & 63;
    int v = (lane < nb) ? blocksum[lane] : 0;
    int sc = v;
    #pragma unroll
    for (int off = 1; off < 64; off <<= 1) {
        int t = __shfl_up(sc, off);
        if (lane >= off) sc += t;
    }
    if (lane < nb) blocksum[lane] = sc - v;             // exclusive
}

// phase 3: add block offsets -> rowptr & pos
__global__ void scan3_k(const int* __restrict__ partial, const int* __restrict__ blocksum,
                        int* __restrict__ rowptr, int* __restrict__ pos) {
    int i = blockIdx.x * blockDim.x + threadIdx.x;
    if (i == 0) rowptr[N_NODES] = E_TOT;                // total is a constant
    if (i >= N_NODES) return;
    int e = partial[i] + blocksum[i >> 10];
    rowptr[i] = e;
    pos[i] = e;
}

__global__ void scatter_k(const int* __restrict__ ei, int* __restrict__ pos,
                          int* __restrict__ csr_src) {
    int e = blockIdx.x * blockDim.x + threadIdx.x;
    if (e >= E_TOT) return;
    int s, d;
    if (e < N_EDGESX) { s = ei[e]; d = ei[N_EDGESX + e]; }
    else              { s = e - N_EDGESX; d = s; }
    int idx = atomicAdd(&pos[d], 1);
    csr_src[idx] = s;
}

// ---------------- fused NO-MAX softmax+aggregate, H=8, C=64 ----------------
__global__ __launch_bounds__(256) void node_agg8_k(
    const int* __restrict__ rowptr, const int* __restrict__ csr_src,
    const float* __restrict__ als, const float* __restrict__ ald,
    const unsigned short* __restrict__ hb, const float* __restrict__ bias,
    short* __restrict__ out) {
    int node = (blockIdx.x << 2) + (threadIdx.x >> 6);
    int lane = threadIdx.x & 63;
    if (node >= N_NODES) return;
    int beg = rowptr[node], end = rowptr[node + 1];
    int eh_e = lane >> 3, eh_h = lane & 7;
    float adv = ald[(size_t)node * 8 + eh_h];
    float den = 0.f;
    float acc[8] = {};
    int i = beg + eh_e;
    int s_cur = csr_src[i < end ? i : (end - 1)];
    for (int c0 = beg; c0 < end; c0 += 8, i += 8) {
        bool valid = (i < end);
        int inx = i + 8;
        int s_next = csr_src[inx < end ? inx : (end - 1)];   // prefetch next chunk
        float v = lrelu(als[(size_t)s_cur * 8 + eh_h] + adv);
        float p = valid ? __expf(v) : 0.f;                   // native v_exp_f32
        den += p;
        #pragma unroll
        for (int e = 0; e < 8; ++e) {
            if (c0 + e >= end) break;              // uniform across wave
            int se = __shfl(s_cur, e * 8);
            const unsigned short* hrow = hb + (size_t)se * HH512;
            #pragma unroll
            for (int j = 0; j < 8; ++j) {
                float pj = __shfl(p, e * 8 + j);
                acc[j] += pj * bf2f(hrow[j * 64 + lane]);
            }
        }
        s_cur = s_next;
    }
    den += __shfl_xor(den, 8);
    den += __shfl_xor(den, 16);
    den += __shfl_xor(den, 32);
    size_t ob = (size_t)node * HH512;
    #pragma unroll
    for (int j = 0; j < 8; ++j) {
        float dj = __shfl(den, j);
        float r = acc[j] / (dj + 1e-16f) + bias[j * 64 + lane];
        out[ob + j * 64 + lane] = f2bf(fmaxf(r, 0.f));
    }
}

// ---------------- final layer: H=1, C=47, NO-MAX softmax + bias + log_softmax ----------------
__global__ __launch_bounds__(256) void node_agg_final_k(
    const int* __restrict__ rowptr, const int* __restrict__ csr_src,
    const float* __restrict__ als, const float* __restrict__ ald,
    const unsigned short* __restrict__ hb, const float* __restrict__ b3,
    float* __restrict__ out) {
    int node = (blockIdx.x << 2) + (threadIdx.x >> 6);
    int lane = threadIdx.x & 63;
    if (node >= N_NODES) return;
    int beg = rowptr[node], end = rowptr[node + 1];
    float ad = ald[node];
    float den = 0.f, acc = 0.f;
    int i = beg + lane;
    int s_cur = csr_src[i < end ? i : (end - 1)];
    for (int c0 = beg; c0 < end; c0 += 64, i += 64) {
        bool valid = (i < end);
        int inx = i + 64;
        int s_next = csr_src[inx < end ? inx : (end - 1)];   // prefetch
        float v = lrelu(als[s_cur] + ad);
        float p = valid ? __expf(v) : 0.f;                   // native v_exp_f32
        den += p;
        #pragma unroll 4
        for (int e = 0; e < 64; ++e) {
            if (c0 + e >= end) break;               // uniform across wave
            int se = __shfl(s_cur, e);
            float pe = __shfl(p, e);
            if (lane < OUTC) acc += pe * bf2f(hb[(size_t)se * OUTC + lane]);
        }
        s_cur = s_next;
    }
    #pragma unroll
    for (int off = 32; off; off >>= 1) den += __shfl_xor(den, off);
    float r = (lane < OUTC) ? acc / (den + 1e-16f) + b3[lane] : -INFINITY;
    float mx = r;
    #pragma unroll
    for (int off = 32; off; off >>= 1) mx = fmaxf(mx, __shfl_xor(mx, off));
    float ex = (lane < OUTC) ? expf(r - mx) : 0.f;
    float sum = ex;
    #pragma unroll
    for (int off = 32; off; off >>= 1) sum += __shfl_xor(sum, off);
    if (lane < OUTC) out[(size_t)node * OUTC + lane] = r - mx - logf(sum);
}

static inline int cdiv(long long a, long long b) { return (int)((a + b - 1) / b); }

extern "C" void kernel_launch(void* const* d_in, const int* in_sizes, int n_in,
                              void* d_out, int out_size, void* d_ws, size_t ws_size,
                              hipStream_t stream) {
    const float* x   = (const float*)d_in[0];
    const int*   ei  = (const int*)d_in[1];
    const float* W1  = (const float*)d_in[2];
    const float* as1 = (const float*)d_in[3];
    const float* ad1 = (const float*)d_in[4];
    const float* b1  = (const float*)d_in[5];
    const float* W2  = (const float*)d_in[6];
    const float* as2 = (const float*)d_in[7];
    const float* ad2 = (const float*)d_in[8];
    const float* b2  = (const float*)d_in[9];
    const float* W3  = (const float*)d_in[10];
    const float* as3 = (const float*)d_in[11];
    const float* ad3 = (const float*)d_in[12];
    const float* b3  = (const float*)d_in[13];
    float* out = (float*)d_out;

    short* Abf = (short*)d_ws;                                     // [N,512] bf16
    unsigned short* Hb = (unsigned short*)(Abf + (size_t)N_NODES * HH512); // [N,512] bf16
    float* als = (float*)(Hb + (size_t)N_NODES * HH512);           // [N,8]
    float* ald = als + (size_t)N_NODES * HEADS;                    // [N,8]
    short* Wt1 = (short*)(ald + (size_t)N_NODES * HEADS);          // [512,256] bf16
    short* Wt2 = Wt1 + (size_t)512 * 256;                          // [512,512] bf16
    short* Wt3 = Wt2 + (size_t)512 * 512;                          // [47,512]  bf16
    int* rowptr  = (int*)(Wt3 + (size_t)47 * 512 + 512);           // [N+1] (+pad)
    int* pos     = rowptr + (N_NODES + 1);                         // [N]
    int* csr_src = pos + N_NODES;                                  // [E_TOT]
    int* blocksum = csr_src + E_TOT;                               // [64]

    dim3 blk(256);
    int nb = cdiv(N_NODES, 1024);   // 49 <= 64

    // ---- CSR build (parallel scan; reused by all 3 layers) ----
    hipMemsetAsync(pos, 0, (size_t)N_NODES * 4, stream);
    deg_count_k<<<cdiv(E_TOT, 256), blk, 0, stream>>>(ei, pos);
    scan1_k<<<nb, 1024, 0, stream>>>(pos, rowptr, blocksum);       // pos=deg -> rowptr=partial
    scan2_k<<<1, 64, 0, stream>>>(blocksum, nb);
    scan3_k<<<cdiv(N_NODES, 256), blk, 0, stream>>>(rowptr, blocksum, rowptr, pos);
    scatter_k<<<cdiv(E_TOT, 256), blk, 0, stream>>>(ei, pos, csr_src);

    // ---- all weight transpose-casts in one launch ----
    wt_cast_all_k<<<cdiv(W1N + W2N + W3N, 256), blk, 0, stream>>>(W1, W2, W3, Wt1, Wt2, Wt3);
    cast_bf16_k<<<cdiv((long long)N_NODES * 256 / 4, 256), blk, 0, stream>>>(x, Abf, (long long)N_NODES * 256);

    // ================= Layer 1 =================
    gemm_bf16<<<dim3(cdiv(N_NODES, GBM), HH512 / GBN), blk, 0, stream>>>(
        Abf, Wt1, Hb, N_NODES, HH512, 256, as1, ad1, als, ald, 64, HEADS);
    node_agg8_k<<<cdiv(N_NODES, 4), blk, 0, stream>>>(rowptr, csr_src, als, ald, Hb, b1, Abf);

    // ================= Layer 2 =================
    gemm_bf16<<<dim3(cdiv(N_NODES, GBM), HH512 / GBN), blk, 0, stream>>>(
        Abf, Wt2, Hb, N_NODES, HH512, HH512, as2, ad2, als, ald, 64, HEADS);
    node_agg8_k<<<cdiv(N_NODES, 4), blk, 0, stream>>>(rowptr, csr_src, als, ald, Hb, b2, Abf);

    // ================= Layer 3 =================
    gemm_bf16<<<dim3(cdiv(N_NODES, GBM), 1), blk, 0, stream>>>(
        Abf, Wt3, Hb, N_NODES, OUTC, HH512, as3, ad3, als, ald, 47, 1);
    node_agg_final_k<<<cdiv(N_NODES, 4), blk, 0, stream>>>(rowptr, csr_src, als, ald, Hb, b3, out);
}